// Round 5
// baseline (248.257 us; speedup 1.0000x reference)
//
#include <hip/hip_runtime.h>
#include <cstdint>

typedef short bf16x8 __attribute__((ext_vector_type(8)));
typedef float f32x4  __attribute__((ext_vector_type(4)));

#define TOK    128        // tokens per block (4 waves x 32)
#define CHUNK  64         // codes per chunk
#define NCH    16         // K / CHUNK
#define PITCH  264        // ushorts/row: 256 + 8 pad (132 dwords = 4 mod 32 -> b128 reads tile banks)
#define HROWS  (64 * PITCH)
#define MAXC   24

__device__ __forceinline__ unsigned short f2bf(float f) {
  unsigned u = __float_as_uint(f);
  return (unsigned short)((u + 0x7FFFu + ((u >> 16) & 1u)) >> 16);
}
__device__ __forceinline__ uint4 pack8(float4 a, float4 b) {
  uint4 u;
  u.x = (unsigned)f2bf(a.x) | ((unsigned)f2bf(a.y) << 16);
  u.y = (unsigned)f2bf(a.z) | ((unsigned)f2bf(a.w) << 16);
  u.z = (unsigned)f2bf(b.x) | ((unsigned)f2bf(b.y) << 16);
  u.w = (unsigned)f2bf(b.z) | ((unsigned)f2bf(b.w) << 16);
  return u;
}

// ---------------------------------------------------------------------------
// Single fused kernel: bf16-MFMA screen + gated candidates + exact fp32
// rescore + epilogue. Block = 256 thr (4 waves) = 128 tokens; wave owns 32
// tokens as 2 MFMA A-sets held ENTIRELY in registers (z reused all chunks).
// LDS buf: z-stage (128x264 us) reused as 2x chunk double-buffer (64x264 us).
// Codebook converted fp32->bf16 during per-chunk staging (cb is L2-resident);
// chunk norms computed there too -> no prep kernel, no cb_bf global.
// ---------------------------------------------------------------------------
__global__ __launch_bounds__(256, 1) void vq_main(
    const float* __restrict__ z, const float* __restrict__ cb,
    const float* __restrict__ mask,
    float* __restrict__ out_q, float* __restrict__ out_idx_f,
    float* __restrict__ out_loss, float* __restrict__ acc2,
    int* __restrict__ done_ctr, int nblocks, int K) {
  __shared__ unsigned short buf[128 * PITCH];   // 67584 B (z-phase / 2x chunk)
  __shared__ float ee_lds[1024];                // 4 KB: all code norms (fp32)
  __shared__ float znorm[TOK];
  __shared__ int   ccnt[TOK];
  __shared__ unsigned short cand[TOK * MAXC];   // 6144 B
  __shared__ float red[8];
  __shared__ bool  last;

  const int t = threadIdx.x;
  const int n0 = blockIdx.x * TOK;
  const int q16 = t & 15;        // staging: 16 lanes per row
  const int rbase = t >> 4;

  // ---- phase 1: stage z -> bf16 LDS (coalesced, conflict-free), ||z|| ----
  #pragma unroll
  for (int pass = 0; pass < 8; ++pass) {
    int row = pass * 16 + rbase;
    const float* zr = z + (size_t)(n0 + row) * 256;
    float ssq = 0.f;
    #pragma unroll
    for (int j = 0; j < 2; ++j) {
      float4 a = *reinterpret_cast<const float4*>(zr + q16 * 8 + j * 128);
      float4 b = *reinterpret_cast<const float4*>(zr + q16 * 8 + j * 128 + 4);
      ssq += a.x*a.x + a.y*a.y + a.z*a.z + a.w*a.w
           + b.x*b.x + b.y*b.y + b.z*b.z + b.w*b.w;
      *reinterpret_cast<uint4*>(&buf[row * PITCH + q16 * 8 + j * 128]) = pack8(a, b);
    }
    #pragma unroll
    for (int off = 1; off < 16; off <<= 1) ssq += __shfl_xor(ssq, off, 64);
    if (q16 == 0) znorm[row] = sqrtf(ssq);
  }
  if (t < TOK) ccnt[t] = 0;
  __syncthreads();

  // ---- phase 2: A fragments (all 8 k-steps x 2 sets) into registers ----
  const int wv = t >> 6, lane = t & 63;
  const int quad = lane >> 4, l15 = lane & 15;
  bf16x8 afrag[2][8];
  #pragma unroll
  for (int s = 0; s < 2; ++s) {
    const unsigned short* za = &buf[(wv * 32 + s * 16 + l15) * PITCH + quad * 8];
    #pragma unroll
    for (int kk = 0; kk < 8; ++kk)
      afrag[s][kk] = *reinterpret_cast<const bf16x8*>(za + kk * 32);
  }
  float znreg[2][4];
  #pragma unroll
  for (int s = 0; s < 2; ++s)
    #pragma unroll
    for (int r = 0; r < 4; ++r)
      znreg[s][r] = znorm[wv * 32 + s * 16 + quad * 4 + r];
  __syncthreads();  // A-loads done before chunk staging overwrites buf

  // ---- stage chunk 0 into half 0 ----
  {
    unsigned short* dst = buf;
    #pragma unroll
    for (int pass = 0; pass < 4; ++pass) {
      int row = pass * 16 + rbase;
      const float* src = cb + (size_t)row * 256;
      float ssq = 0.f;
      #pragma unroll
      for (int j = 0; j < 2; ++j) {
        float4 a = *reinterpret_cast<const float4*>(src + q16 * 8 + j * 128);
        float4 b = *reinterpret_cast<const float4*>(src + q16 * 8 + j * 128 + 4);
        ssq += a.x*a.x + a.y*a.y + a.z*a.z + a.w*a.w
             + b.x*b.x + b.y*b.y + b.z*b.z + b.w*b.w;
        *reinterpret_cast<uint4*>(&dst[row * PITCH + q16 * 8 + j * 128]) = pack8(a, b);
      }
      #pragma unroll
      for (int off = 1; off < 16; off <<= 1) ssq += __shfl_xor(ssq, off, 64);
      if (q16 == 0) ee_lds[row] = ssq;
    }
  }
  __syncthreads();

  float amin[2][4];
  #pragma unroll
  for (int s = 0; s < 2; ++s)
    #pragma unroll
    for (int r = 0; r < 4; ++r) amin[s][r] = 3.4e38f;

  // ---- phase 3: chunk loop (double-buffered; 1 barrier/chunk) ----
  for (int ch = 0; ch < NCH; ++ch) {
    // stage chunk ch+1 into the other half while computing this one
    if (ch + 1 < NCH) {
      unsigned short* dst = buf + ((ch + 1) & 1) * HROWS;
      int kb = (ch + 1) * CHUNK;
      #pragma unroll
      for (int pass = 0; pass < 4; ++pass) {
        int row = pass * 16 + rbase;
        const float* src = cb + (size_t)(kb + row) * 256;
        float ssq = 0.f;
        #pragma unroll
        for (int j = 0; j < 2; ++j) {
          float4 a = *reinterpret_cast<const float4*>(src + q16 * 8 + j * 128);
          float4 b = *reinterpret_cast<const float4*>(src + q16 * 8 + j * 128 + 4);
          ssq += a.x*a.x + a.y*a.y + a.z*a.z + a.w*a.w
               + b.x*b.x + b.y*b.y + b.z*b.z + b.w*b.w;
          *reinterpret_cast<uint4*>(&dst[row * PITCH + q16 * 8 + j * 128]) = pack8(a, b);
        }
        #pragma unroll
        for (int off = 1; off < 16; off <<= 1) ssq += __shfl_xor(ssq, off, 64);
        if (q16 == 0) ee_lds[kb + row] = ssq;
      }
    }

    // MFMA on current half: 32 B-reads feed 64 MFMAs (2 A-sets)
    const unsigned short* cbb = buf + (ch & 1) * HROWS;
    f32x4 acc[2][4];
    #pragma unroll
    for (int s = 0; s < 2; ++s)
      #pragma unroll
      for (int ct = 0; ct < 4; ++ct) acc[s][ct] = (f32x4){0.f, 0.f, 0.f, 0.f};
    #pragma unroll
    for (int kk = 0; kk < 8; ++kk) {
      bf16x8 b0 = *reinterpret_cast<const bf16x8*>(&cbb[(l15)        * PITCH + quad * 8 + kk * 32]);
      bf16x8 b1 = *reinterpret_cast<const bf16x8*>(&cbb[(16 + l15)   * PITCH + quad * 8 + kk * 32]);
      bf16x8 b2 = *reinterpret_cast<const bf16x8*>(&cbb[(32 + l15)   * PITCH + quad * 8 + kk * 32]);
      bf16x8 b3 = *reinterpret_cast<const bf16x8*>(&cbb[(48 + l15)   * PITCH + quad * 8 + kk * 32]);
      acc[0][0] = __builtin_amdgcn_mfma_f32_16x16x32_bf16(afrag[0][kk], b0, acc[0][0], 0, 0, 0);
      acc[1][0] = __builtin_amdgcn_mfma_f32_16x16x32_bf16(afrag[1][kk], b0, acc[1][0], 0, 0, 0);
      acc[0][1] = __builtin_amdgcn_mfma_f32_16x16x32_bf16(afrag[0][kk], b1, acc[0][1], 0, 0, 0);
      acc[1][1] = __builtin_amdgcn_mfma_f32_16x16x32_bf16(afrag[1][kk], b1, acc[1][1], 0, 0, 0);
      acc[0][2] = __builtin_amdgcn_mfma_f32_16x16x32_bf16(afrag[0][kk], b2, acc[0][2], 0, 0, 0);
      acc[1][2] = __builtin_amdgcn_mfma_f32_16x16x32_bf16(afrag[1][kk], b2, acc[1][2], 0, 0, 0);
      acc[0][3] = __builtin_amdgcn_mfma_f32_16x16x32_bf16(afrag[0][kk], b3, acc[0][3], 0, 0, 0);
      acc[1][3] = __builtin_amdgcn_mfma_f32_16x16x32_bf16(afrag[1][kk], b3, acc[1][3], 0, 0, 0);
    }

    // gate: running min + candidate append
    float e[4], en[4];
    #pragma unroll
    for (int ct = 0; ct < 4; ++ct) {
      e[ct]  = ee_lds[ch * 64 + ct * 16 + l15];
      en[ct] = sqrtf(e[ct]);
    }
    #pragma unroll
    for (int s = 0; s < 2; ++s) {
      #pragma unroll
      for (int r = 0; r < 4; ++r) {
        float d0 = e[0] - 2.f * acc[s][0][r];
        float d1 = e[1] - 2.f * acc[s][1][r];
        float d2 = e[2] - 2.f * acc[s][2][r];
        float d3 = e[3] - 2.f * acc[s][3][r];
        float w = fminf(fminf(d0, d1), fminf(d2, d3));
        #pragma unroll
        for (int off = 1; off < 16; off <<= 1) w = fminf(w, __shfl_xor(w, off, 64));
        float am = fminf(amin[s][r], w);
        amin[s][r] = am;
        int tok = wv * 32 + s * 16 + quad * 4 + r;
        float thr = am + 1.5f + 0.002f * znreg[s][r] * en[0];  // en varies <..>
        // margin covers 2-sided bf16 screen error (~30 sigma)
        if (d0 <= am + 1.5f + 0.002f * znreg[s][r] * en[0]) {
          int sl = atomicAdd(&ccnt[tok], 1);
          if (sl < MAXC) cand[tok * MAXC + sl] = (unsigned short)(ch * 64 + l15);
        }
        if (d1 <= am + 1.5f + 0.002f * znreg[s][r] * en[1]) {
          int sl = atomicAdd(&ccnt[tok], 1);
          if (sl < MAXC) cand[tok * MAXC + sl] = (unsigned short)(ch * 64 + 16 + l15);
        }
        if (d2 <= am + 1.5f + 0.002f * znreg[s][r] * en[2]) {
          int sl = atomicAdd(&ccnt[tok], 1);
          if (sl < MAXC) cand[tok * MAXC + sl] = (unsigned short)(ch * 64 + 32 + l15);
        }
        if (d3 <= am + 1.5f + 0.002f * znreg[s][r] * en[3]) {
          int sl = atomicAdd(&ccnt[tok], 1);
          if (sl < MAXC) cand[tok * MAXC + sl] = (unsigned short)(ch * 64 + 48 + l15);
        }
        (void)thr;
      }
    }
    __syncthreads();
  }

  // ---- phase 4: exact fp32 rescore + epilogue (wave per token) ----
  float lsum = 0.f, msum = 0.f;
  for (int it = 0; it < TOK / 4; ++it) {
    int tok = it * 4 + wv;
    int n = n0 + tok;
    float4 zv = *reinterpret_cast<const float4*>(z + (size_t)n * 256 + lane * 4);
    int cnt = ccnt[tok];
    float bs = 3.4e38f; int bk = 0;
    if (cnt > MAXC) {  // overflow fallback: exact scan of all K (never in practice)
      for (int k = 0; k < K; ++k) {
        float4 ev = *reinterpret_cast<const float4*>(cb + (size_t)k * 256 + lane * 4);
        float dp = zv.x * ev.x + zv.y * ev.y + zv.z * ev.z + zv.w * ev.w;
        #pragma unroll
        for (int off = 32; off; off >>= 1) dp += __shfl_xor(dp, off, 64);
        float s = ee_lds[k] - 2.f * dp;
        if (s < bs) { bs = s; bk = k; }
      }
    } else {
      for (int c = 0; c < cnt; ++c) {
        int k = cand[tok * MAXC + c];
        float4 ev = *reinterpret_cast<const float4*>(cb + (size_t)k * 256 + lane * 4);
        float dp = zv.x * ev.x + zv.y * ev.y + zv.z * ev.z + zv.w * ev.w;
        #pragma unroll
        for (int off = 32; off; off >>= 1) dp += __shfl_xor(dp, off, 64);
        float s = ee_lds[k] - 2.f * dp;
        if (s < bs || (s == bs && k < bk)) { bs = s; bk = k; }
      }
    }
    float m = mask[n];
    float4 qv = *reinterpret_cast<const float4*>(cb + (size_t)bk * 256 + lane * 4);
    float4 o; o.x = qv.x * m; o.y = qv.y * m; o.z = qv.z * m; o.w = qv.w * m;
    *reinterpret_cast<float4*>(out_q + (size_t)n * 256 + lane * 4) = o;
    float dx = zv.x - qv.x, dy = zv.y - qv.y, dz = zv.z - qv.z, dw = zv.w - qv.w;
    lsum = fmaf(m, dx * dx + dy * dy + dz * dz + dw * dw, lsum);
    if (lane == 0) {
      msum += m;
      out_idx_f[n] = (m > 0.f) ? (float)bk : 0.f;
    }
  }
  #pragma unroll
  for (int off = 32; off; off >>= 1) lsum += __shfl_down(lsum, off, 64);
  if (lane == 0) { red[wv] = lsum; red[4 + wv] = msum; }
  __syncthreads();
  if (t == 0) {
    atomicAdd(&acc2[0], red[0] + red[1] + red[2] + red[3]);
    atomicAdd(&acc2[1], red[4] + red[5] + red[6] + red[7]);
    __threadfence();
    int prev = atomicAdd(done_ctr, 1);
    last = (prev == nblocks - 1);
  }
  __syncthreads();
  if (last && t == 0) {
    float s  = atomicAdd(&acc2[0], 0.0f);
    float nv = atomicAdd(&acc2[1], 0.0f);
    out_loss[0] = (nv > 0.f) ? (0.25f * s / (nv * 256.0f)) : 0.0f;
  }
}

// ---------------------------------------------------------------------------
extern "C" void kernel_launch(void* const* d_in, const int* in_sizes, int n_in,
                              void* d_out, int out_size, void* d_ws, size_t ws_size,
                              hipStream_t stream) {
  const float* z    = (const float*)d_in[0];  // (N, 256)
  const float* mask = (const float*)d_in[1];  // (N,)
  const float* cb   = (const float*)d_in[2];  // (K, 256)
  const int N = in_sizes[1];                  // 32768
  const int D = 256;
  const int K = in_sizes[2] / D;              // 1024

  float* wsf  = (float*)d_ws;
  float* acc2 = wsf;                          // 2 floats
  int*   dctr = (int*)(wsf + 2);              // 1 int

  float* out_q     = (float*)d_out;           // N*D
  float* out_loss  = out_q + (size_t)N * D;   // 1
  float* out_idx_f = out_loss + 1;            // N

  hipMemsetAsync(wsf, 0, 12, stream);
  vq_main<<<N / TOK, 256, 0, stream>>>(z, cb, mask, out_q, out_idx_f,
                                       out_loss, acc2, dctr, N / TOK, K);
}